// Round 1
// baseline (434.833 us; speedup 1.0000x reference)
//
#include <hip/hip_runtime.h>
#include <hip/hip_bf16.h>

#define H0 200
#define W0 304
#define H1 100
#define W1 152
#define H2 50
#define W2 76
#define CPL 256   // channels per level
#define CTOT 768
#define OH 7
#define OW 7

// Value of the bilinear-upsampled (half-pixel, align_corners=False) image at
// INTEGER fine-grid coords (yf, xf). Exact: coarse coord = (fine+0.5)*inv_s-0.5,
// clamped (equivalent to jax.image.resize edge renormalization).
__device__ __forceinline__ float upsampled_at(const float* __restrict__ f,
                                              int Hc, int Wc, float inv_s,
                                              int yf, int xf) {
    float yc = ((float)yf + 0.5f) * inv_s - 0.5f;
    float xc = ((float)xf + 0.5f) * inv_s - 0.5f;
    yc = fminf(fmaxf(yc, 0.0f), (float)(Hc - 1));
    xc = fminf(fmaxf(xc, 0.0f), (float)(Wc - 1));
    int y0 = (int)yc, x0 = (int)xc;
    int y1 = min(y0 + 1, Hc - 1), x1 = min(x0 + 1, Wc - 1);
    float ly = yc - (float)y0, lx = xc - (float)x0;
    float hy = 1.0f - ly, hx = 1.0f - lx;
    float v00 = f[y0 * Wc + x0], v01 = f[y0 * Wc + x1];
    float v10 = f[y1 * Wc + x0], v11 = f[y1 * Wc + x1];
    return hy * (hx * v00 + lx * v01) + ly * (hx * v10 + lx * v11);
}

__global__ void __launch_bounds__(256)
roi_align_fused_kernel(const float* __restrict__ f0,
                       const float* __restrict__ f1,
                       const float* __restrict__ f2,
                       const float* __restrict__ boxes,
                       const int* __restrict__ img_h_p,
                       const int* __restrict__ img_w_p,
                       float* __restrict__ out,
                       int total) {
    int i = blockIdx.x * blockDim.x + threadIdx.x;
    if (i >= total) return;

    int ow = i % OW;
    int t  = i / OW;
    int oh = t % OH;
    t /= OH;
    int c  = t % CTOT;
    int n  = t / CTOT;

    float sx = (float)W0 / (float)img_w_p[0];
    float sy = (float)H0 / (float)img_h_p[0];

    float bx1 = boxes[n * 4 + 0] * sx;
    float by1 = boxes[n * 4 + 1] * sy;
    float bx2 = boxes[n * 4 + 2] * sx;
    float by2 = boxes[n * 4 + 3] * sy;
    float rw = fmaxf(bx2 - bx1, 1.0f);
    float rh = fmaxf(by2 - by1, 1.0f);
    float bw = rw / (float)OW;
    float bh = rh / (float)OH;

    int level = c >> 8;       // 256 channels per level
    int cl = c & (CPL - 1);
    const float* f;
    int Hc, Wc;
    float inv_s;
    if (level == 0)      { f = f0 + (size_t)cl * (H0 * W0); Hc = H0; Wc = W0; inv_s = 1.0f;  }
    else if (level == 1) { f = f1 + (size_t)cl * (H1 * W1); Hc = H1; Wc = W1; inv_s = 0.5f;  }
    else                 { f = f2 + (size_t)cl * (H2 * W2); Hc = H2; Wc = W2; inv_s = 0.25f; }

    float acc = 0.0f;
#pragma unroll
    for (int ry = 0; ry < 2; ++ry) {
        float Y = by1 + ((float)oh + 0.25f + 0.5f * (float)ry) * bh;
        bool vy = (Y >= -1.0f) && (Y <= (float)H0);
        float Yc = fminf(fmaxf(Y, 0.0f), (float)(H0 - 1));
        int y0 = (int)Yc;
        int y1i = min(y0 + 1, H0 - 1);
        float ly = Yc - (float)y0;
        float hy = 1.0f - ly;
#pragma unroll
        for (int rx = 0; rx < 2; ++rx) {
            float X = bx1 + ((float)ow + 0.25f + 0.5f * (float)rx) * bw;
            bool vx = (X >= -1.0f) && (X <= (float)W0);
            float Xc = fminf(fmaxf(X, 0.0f), (float)(W0 - 1));
            int x0 = (int)Xc;
            int x1i = min(x0 + 1, W0 - 1);
            float lx = Xc - (float)x0;
            float hx = 1.0f - lx;

            float v;
            if (level == 0) {
                float v00 = f[y0 * W0 + x0],  v01 = f[y0 * W0 + x1i];
                float v10 = f[y1i * W0 + x0], v11 = f[y1i * W0 + x1i];
                v = hy * (hx * v00 + lx * v01) + ly * (hx * v10 + lx * v11);
            } else {
                float u00 = upsampled_at(f, Hc, Wc, inv_s, y0,  x0);
                float u01 = upsampled_at(f, Hc, Wc, inv_s, y0,  x1i);
                float u10 = upsampled_at(f, Hc, Wc, inv_s, y1i, x0);
                float u11 = upsampled_at(f, Hc, Wc, inv_s, y1i, x1i);
                v = hy * (hx * u00 + lx * u01) + ly * (hx * u10 + lx * u11);
            }
            if (vy && vx) acc += v;
        }
    }
    out[i] = acc * 0.25f;
}

extern "C" void kernel_launch(void* const* d_in, const int* in_sizes, int n_in,
                              void* d_out, int out_size, void* d_ws, size_t ws_size,
                              hipStream_t stream) {
    const float* f0    = (const float*)d_in[0];
    const float* f1    = (const float*)d_in[1];
    const float* f2    = (const float*)d_in[2];
    const float* boxes = (const float*)d_in[3];
    const int* img_h_p = (const int*)d_in[4];
    const int* img_w_p = (const int*)d_in[5];
    float* out = (float*)d_out;

    int N = in_sizes[3] / 4;              // 256 boxes
    int total = N * CTOT * OH * OW;       // == out_size

    int block = 256;
    int grid = (total + block - 1) / block;
    roi_align_fused_kernel<<<grid, block, 0, stream>>>(
        f0, f1, f2, boxes, img_h_p, img_w_p, out, total);
}

// Round 2
// 314.393 us; speedup vs baseline: 1.3831x; 1.3831x over previous
//
#include <hip/hip_runtime.h>
#include <hip/hip_bf16.h>

#define H0 200
#define W0 304
#define H1 100
#define W1 152
#define H2 50
#define W2 76
#define CPL 256   // channels per level
#define CTOT 768
#define OH 7
#define OW 7

// Composed 1D weights: RoIAlign bilinear over fine corners (yf0, yf0+1) where
// each fine corner value is a half-pixel bilinear of the coarse map.
// All coarse taps fall in {base, base+1, base+2} since inv_s <= 0.5.
// w[r] = hf*hat(yc0, base+r) + lf*hat(yc1, base+r). Exact incl. clamped edges
// (clamped coords make out-of-range taps get zero hat weight).
__device__ __forceinline__ void axis_w3(int yf0, int Hf, int Hc, float inv_s,
                                        float lf, int& base, float* w) {
    int yf1 = min(yf0 + 1, Hf - 1);
    float hf = 1.0f - lf;
    float yc0 = ((float)yf0 + 0.5f) * inv_s - 0.5f;
    float yc1 = ((float)yf1 + 0.5f) * inv_s - 0.5f;
    yc0 = fminf(fmaxf(yc0, 0.0f), (float)(Hc - 1));
    yc1 = fminf(fmaxf(yc1, 0.0f), (float)(Hc - 1));
    base = (int)yc0;
#pragma unroll
    for (int r = 0; r < 3; ++r) {
        float j = (float)(base + r);
        float h0 = fmaxf(0.0f, 1.0f - fabsf(yc0 - j));
        float h1 = fmaxf(0.0f, 1.0f - fabsf(yc1 - j));
        w[r] = hf * h0 + lf * h1;
    }
}

__global__ void __launch_bounds__(256)
roi_align_fused_kernel(const float* __restrict__ f0,
                       const float* __restrict__ f1,
                       const float* __restrict__ f2,
                       const float* __restrict__ boxes,
                       const int* __restrict__ img_h_p,
                       const int* __restrict__ img_w_p,
                       float* __restrict__ out,
                       int total) {
    int i = blockIdx.x * blockDim.x + threadIdx.x;
    if (i >= total) return;

    int ow = i % OW;
    int t  = i / OW;
    int oh = t % OH;
    t /= OH;
    int c  = t % CTOT;
    int n  = t / CTOT;

    float sx = (float)W0 / (float)img_w_p[0];
    float sy = (float)H0 / (float)img_h_p[0];

    float bx1 = boxes[n * 4 + 0] * sx;
    float by1 = boxes[n * 4 + 1] * sy;
    float bx2 = boxes[n * 4 + 2] * sx;
    float by2 = boxes[n * 4 + 3] * sy;
    float bw = fmaxf(bx2 - bx1, 1.0f) * (1.0f / (float)OW);
    float bh = fmaxf(by2 - by1, 1.0f) * (1.0f / (float)OH);

    int level = c >> 8;       // 256 channels per level
    int cl = c & (CPL - 1);
    const float* f;
    int Hc, Wc;
    float inv_s;
    if (level == 0)      { f = f0 + (size_t)cl * (H0 * W0); Hc = H0; Wc = W0; inv_s = 1.0f;  }
    else if (level == 1) { f = f1 + (size_t)cl * (H1 * W1); Hc = H1; Wc = W1; inv_s = 0.5f;  }
    else                 { f = f2 + (size_t)cl * (H2 * W2); Hc = H2; Wc = W2; inv_s = 0.25f; }

    // ---- per-axis sample geometry (independent of the other axis) ----
    // y axis: 2 samples (ry=0,1)
    bool  vy[2];
    int   ybase[2];        // level>0: coarse 3-tap base; level0: y0
    int   y1i_l0[2];
    float wy3[2][3];       // level>0 composed weights
    float ly_l0[2], hy_l0[2];
#pragma unroll
    for (int ry = 0; ry < 2; ++ry) {
        float Y = by1 + ((float)oh + 0.25f + 0.5f * (float)ry) * bh;
        vy[ry] = (Y >= -1.0f) && (Y <= (float)H0);
        float Yc = fminf(fmaxf(Y, 0.0f), (float)(H0 - 1));
        int y0 = (int)Yc;
        float ly = Yc - (float)y0;
        if (level == 0) {
            ybase[ry] = y0;
            y1i_l0[ry] = min(y0 + 1, H0 - 1);
            ly_l0[ry] = ly; hy_l0[ry] = 1.0f - ly;
        } else {
            axis_w3(y0, H0, Hc, inv_s, ly, ybase[ry], wy3[ry]);
        }
    }
    // x axis: 2 samples (rx=0,1)
    bool  vx[2];
    int   xbase[2];
    int   x1i_l0[2];
    float wx3[2][3];
    float lx_l0[2], hx_l0[2];
#pragma unroll
    for (int rx = 0; rx < 2; ++rx) {
        float X = bx1 + ((float)ow + 0.25f + 0.5f * (float)rx) * bw;
        vx[rx] = (X >= -1.0f) && (X <= (float)W0);
        float Xc = fminf(fmaxf(X, 0.0f), (float)(W0 - 1));
        int x0 = (int)Xc;
        float lx = Xc - (float)x0;
        if (level == 0) {
            xbase[rx] = x0;
            x1i_l0[rx] = min(x0 + 1, W0 - 1);
            lx_l0[rx] = lx; hx_l0[rx] = 1.0f - lx;
        } else {
            axis_w3(x0, W0, Wc, inv_s, lx, xbase[rx], wx3[rx]);
        }
    }

    float acc = 0.0f;
    if (level == 0) {
#pragma unroll
        for (int ry = 0; ry < 2; ++ry) {
            int r0 = ybase[ry] * W0, r1 = y1i_l0[ry] * W0;
#pragma unroll
            for (int rx = 0; rx < 2; ++rx) {
                int c0 = xbase[rx], c1 = x1i_l0[rx];
                float v00 = f[r0 + c0], v01 = f[r0 + c1];
                float v10 = f[r1 + c0], v11 = f[r1 + c1];
                float v = hy_l0[ry] * (hx_l0[rx] * v00 + lx_l0[rx] * v01)
                        + ly_l0[ry] * (hx_l0[rx] * v10 + lx_l0[rx] * v11);
                if (vy[ry] && vx[rx]) acc += v;
            }
        }
    } else {
#pragma unroll
        for (int ry = 0; ry < 2; ++ry) {
            int rr0 = min(ybase[ry] + 0, Hc - 1) * Wc;
            int rr1 = min(ybase[ry] + 1, Hc - 1) * Wc;
            int rr2 = min(ybase[ry] + 2, Hc - 1) * Wc;
#pragma unroll
            for (int rx = 0; rx < 2; ++rx) {
                int c0 = min(xbase[rx] + 0, Wc - 1);
                int c1 = min(xbase[rx] + 1, Wc - 1);
                int c2 = min(xbase[rx] + 2, Wc - 1);
                const float* w = wx3[rx];
                float s0 = w[0] * f[rr0 + c0] + w[1] * f[rr0 + c1] + w[2] * f[rr0 + c2];
                float s1 = w[0] * f[rr1 + c0] + w[1] * f[rr1 + c1] + w[2] * f[rr1 + c2];
                float s2 = w[0] * f[rr2 + c0] + w[1] * f[rr2 + c1] + w[2] * f[rr2 + c2];
                float v = wy3[ry][0] * s0 + wy3[ry][1] * s1 + wy3[ry][2] * s2;
                if (vy[ry] && vx[rx]) acc += v;
            }
        }
    }
    out[i] = acc * 0.25f;
}

extern "C" void kernel_launch(void* const* d_in, const int* in_sizes, int n_in,
                              void* d_out, int out_size, void* d_ws, size_t ws_size,
                              hipStream_t stream) {
    const float* f0    = (const float*)d_in[0];
    const float* f1    = (const float*)d_in[1];
    const float* f2    = (const float*)d_in[2];
    const float* boxes = (const float*)d_in[3];
    const int* img_h_p = (const int*)d_in[4];
    const int* img_w_p = (const int*)d_in[5];
    float* out = (float*)d_out;

    int N = in_sizes[3] / 4;              // 256 boxes
    int total = N * CTOT * OH * OW;       // == out_size

    int block = 256;
    int grid = (total + block - 1) / block;
    roi_align_fused_kernel<<<grid, block, 0, stream>>>(
        f0, f1, f2, boxes, img_h_p, img_w_p, out, total);
}

// Round 3
// 297.025 us; speedup vs baseline: 1.4640x; 1.0585x over previous
//
#include <hip/hip_runtime.h>
#include <hip/hip_bf16.h>

#define H0 200
#define W0 304
#define H1 100
#define W1 152
#define H2 50
#define W2 76
#define CPL 256   // channels per level
#define CTOT 768
#define OH 7
#define OW 7
#define NPOS 49

#define P0 (H0*W0)   // 60800
#define P1 (H1*W1)   // 15200
#define P2 (H2*W2)   // 3800
#define T0_OFF ((size_t)0)
#define T1_OFF ((size_t)P0*CPL)                       // 15,564,800 elems
#define T2_OFF ((size_t)P0*CPL + (size_t)P1*CPL)      // 19,456,000 elems
#define WS_ELEMS ((size_t)P0*CPL + (size_t)P1*CPL + (size_t)P2*CPL) // 20,428,800
#define WS_BYTES (WS_ELEMS * 4)                       // 81,715,200 B

// ---------------- Stage 1: [C][P] -> [P][C] channels-last transpose ----------
__global__ void __launch_bounds__(256)
transpose_cl_kernel(const float* __restrict__ in, float* __restrict__ out, int P) {
    __shared__ float tile[64][65];
    int p_base = blockIdx.x * 64;
    int c_base = blockIdx.y * 64;
    int px = threadIdx.x & 63;
    int cy = threadIdx.x >> 6;
#pragma unroll
    for (int i = 0; i < 16; ++i) {
        int cc = cy + i * 4;
        int p = p_base + px;
        tile[cc][px] = (p < P) ? in[(size_t)(c_base + cc) * P + p] : 0.0f;
    }
    __syncthreads();
    int cx = threadIdx.x & 63;
    int py = threadIdx.x >> 6;
#pragma unroll
    for (int i = 0; i < 16; ++i) {
        int pp = py + i * 4;
        int p = p_base + pp;
        if (p < P) out[(size_t)p * CPL + c_base + cx] = tile[cx][pp];
    }
}

// ---------------- Stage 2 helpers -------------------------------------------
__device__ __forceinline__ float hat01(float d) {
    return fmaxf(0.0f, 1.0f - fabsf(d));
}

// Merged separable window for one output bin on one axis (levels 1/2).
// Composes: RoIAlign 2-sample average x fine-corner bilinear x upsample bilinear.
// Produces base + up-to-6 weights on the coarse grid (delta <= 3 by geometry:
// sample gap <= 4.86 fine px * inv_s <= 2.43 coarse px).
// Validity (sample in [-1, Hf]) folded into the weights (masks factor per axis).
__device__ __forceinline__ void make_axis_window(int o, float b1, float bs,
                                                 int Hc, float inv_s, int Hf,
                                                 float* w, int& base, int& nwin) {
    int bases[2];
    float w3[2][3];
#pragma unroll
    for (int r = 0; r < 2; ++r) {
        float Y = b1 + ((float)o + 0.25f + 0.5f * (float)r) * bs;
        bool v = (Y >= -1.0f) && (Y <= (float)Hf);
        float Yc = fminf(fmaxf(Y, 0.0f), (float)(Hf - 1));
        int y0 = (int)Yc;
        float lf = Yc - (float)y0;
        float hf = 1.0f - lf;
        int yf1 = min(y0 + 1, Hf - 1);
        float yc0 = fminf(fmaxf(((float)y0 + 0.5f) * inv_s - 0.5f, 0.0f), (float)(Hc - 1));
        float yc1 = fminf(fmaxf(((float)yf1 + 0.5f) * inv_s - 0.5f, 0.0f), (float)(Hc - 1));
        int b = (int)yc0;
        bases[r] = b;
#pragma unroll
        for (int t = 0; t < 3; ++t) {
            float j = (float)(b + t);
            float ww = hf * hat01(yc0 - j) + lf * hat01(yc1 - j);
            w3[r][t] = v ? ww : 0.0f;
        }
    }
    base = bases[0];
    int d = bases[1] - bases[0];         // 0..3 by geometry
    nwin = d + 3;
#pragma unroll
    for (int t = 0; t < 6; ++t) w[t] = 0.0f;
    w[0] += w3[0][0]; w[1] += w3[0][1]; w[2] += w3[0][2];
    w[d] += w3[1][0]; w[d + 1] += w3[1][1]; w[d + 2] += w3[1][2];
}

// ---------------- Stage 2: channels-last RoIAlign ---------------------------
// block = (box n, channel-group cg of 64). wave w handles pos = w, w+4, ...
// lane = channel within group -> every tap load is 256B contiguous.
__global__ void __launch_bounds__(256)
roi_align_cl_kernel(const float* __restrict__ T0,
                    const float* __restrict__ T1,
                    const float* __restrict__ T2,
                    const float* __restrict__ boxes,
                    const int* __restrict__ img_h_p,
                    const int* __restrict__ img_w_p,
                    float* __restrict__ out) {
    __shared__ float lds[NPOS][65];
    int n = blockIdx.x;
    int cg = blockIdx.y;                  // 0..11
    int lane = threadIdx.x & 63;
    int wv = threadIdx.x >> 6;            // 0..3
    int level = cg >> 2;
    int c_in_level = ((cg & 3) << 6) + lane;

    const float* T;
    int Hc, Wc;
    float inv_s;
    if (level == 0)      { T = T0; Hc = H0; Wc = W0; inv_s = 1.0f;  }
    else if (level == 1) { T = T1; Hc = H1; Wc = W1; inv_s = 0.5f;  }
    else                 { T = T2; Hc = H2; Wc = W2; inv_s = 0.25f; }
    const float* Tc = T + c_in_level;

    float sx = (float)W0 / (float)img_w_p[0];
    float sy = (float)H0 / (float)img_h_p[0];
    float bx1 = boxes[n * 4 + 0] * sx;
    float by1 = boxes[n * 4 + 1] * sy;
    float bw = fmaxf(boxes[n * 4 + 2] * sx - bx1, 1.0f) * (1.0f / (float)OW);
    float bh = fmaxf(boxes[n * 4 + 3] * sy - by1, 1.0f) * (1.0f / (float)OH);

    for (int pos = wv; pos < NPOS; pos += 4) {
        int oh = pos / 7;
        int ow = pos - oh * 7;
        float acc = 0.0f;

        if (level == 0) {
            // direct path: 2x2 samples x 4 bilinear taps, fine grid == coarse grid
#pragma unroll
            for (int ry = 0; ry < 2; ++ry) {
                float Y = by1 + ((float)oh + 0.25f + 0.5f * (float)ry) * bh;
                bool vy = (Y >= -1.0f) && (Y <= (float)H0);
                float Yc = fminf(fmaxf(Y, 0.0f), (float)(H0 - 1));
                int y0 = (int)Yc;
                int y1i = min(y0 + 1, H0 - 1);
                float ly = Yc - (float)y0, hy = 1.0f - ly;
                size_t r0 = (size_t)(y0 * W0) * CPL;
                size_t r1 = (size_t)(y1i * W0) * CPL;
#pragma unroll
                for (int rx = 0; rx < 2; ++rx) {
                    float X = bx1 + ((float)ow + 0.25f + 0.5f * (float)rx) * bw;
                    bool vx = (X >= -1.0f) && (X <= (float)W0);
                    float Xc = fminf(fmaxf(X, 0.0f), (float)(W0 - 1));
                    int x0 = (int)Xc;
                    int x1i = min(x0 + 1, W0 - 1);
                    float lx = Xc - (float)x0, hx = 1.0f - lx;
                    float v00 = Tc[r0 + (size_t)x0 * CPL];
                    float v01 = Tc[r0 + (size_t)x1i * CPL];
                    float v10 = Tc[r1 + (size_t)x0 * CPL];
                    float v11 = Tc[r1 + (size_t)x1i * CPL];
                    float v = hy * (hx * v00 + lx * v01) + ly * (hx * v10 + lx * v11);
                    if (vy && vx) acc += v;
                }
            }
        } else {
            // merged separable window: <=6 taps per axis covering all 4 samples
            float wy[6], wx[6];
            int yb, xb, yn, xn;
            make_axis_window(oh, by1, bh, Hc, inv_s, H0, wy, yb, yn);
            make_axis_window(ow, bx1, bw, Wc, inv_s, W0, wx, xb, xn);
            for (int a = 0; a < yn; ++a) {
                int row = min(yb + a, Hc - 1);
                const float* rp = Tc + (size_t)(row * Wc) * CPL;
                float wya = wy[a];
                float rsum = 0.0f;
                for (int b = 0; b < xn; ++b) {
                    int col = min(xb + b, Wc - 1);
                    rsum += wx[b] * rp[(size_t)col * CPL];
                }
                acc += wya * rsum;
            }
        }
        lds[pos][lane] = acc * 0.25f;
    }
    __syncthreads();

    // coalesced write-out: consecutive idx -> consecutive (c, pos) addresses
    size_t obase = ((size_t)n * CTOT + (size_t)cg * 64) * NPOS;
    for (int idx = threadIdx.x; idx < 64 * NPOS; idx += 256) {
        int cl = idx / NPOS;
        int pos = idx - cl * NPOS;
        out[obase + idx] = lds[pos][cl];
    }
}

// ---------------- Fallback (R1 kernel) if ws too small ----------------------
__device__ __forceinline__ void axis_w3_fb(int yf0, int Hf, int Hc, float inv_s,
                                           float lf, int& base, float* w) {
    int yf1 = min(yf0 + 1, Hf - 1);
    float hf = 1.0f - lf;
    float yc0 = fminf(fmaxf(((float)yf0 + 0.5f) * inv_s - 0.5f, 0.0f), (float)(Hc - 1));
    float yc1 = fminf(fmaxf(((float)yf1 + 0.5f) * inv_s - 0.5f, 0.0f), (float)(Hc - 1));
    base = (int)yc0;
#pragma unroll
    for (int r = 0; r < 3; ++r) {
        float j = (float)(base + r);
        w[r] = hf * hat01(yc0 - j) + lf * hat01(yc1 - j);
    }
}

__global__ void __launch_bounds__(256)
roi_align_fused_fb_kernel(const float* __restrict__ f0,
                          const float* __restrict__ f1,
                          const float* __restrict__ f2,
                          const float* __restrict__ boxes,
                          const int* __restrict__ img_h_p,
                          const int* __restrict__ img_w_p,
                          float* __restrict__ out,
                          int total) {
    int i = blockIdx.x * blockDim.x + threadIdx.x;
    if (i >= total) return;
    int ow = i % OW;
    int t = i / OW;
    int oh = t % OH; t /= OH;
    int c = t % CTOT;
    int n = t / CTOT;
    float sx = (float)W0 / (float)img_w_p[0];
    float sy = (float)H0 / (float)img_h_p[0];
    float bx1 = boxes[n * 4 + 0] * sx;
    float by1 = boxes[n * 4 + 1] * sy;
    float bw = fmaxf(boxes[n * 4 + 2] * sx - bx1, 1.0f) / OW;
    float bh = fmaxf(boxes[n * 4 + 3] * sy - by1, 1.0f) / OH;
    int level = c >> 8;
    int cl = c & (CPL - 1);
    const float* f;
    int Hc, Wc; float inv_s;
    if (level == 0)      { f = f0 + (size_t)cl * P0; Hc = H0; Wc = W0; inv_s = 1.0f;  }
    else if (level == 1) { f = f1 + (size_t)cl * P1; Hc = H1; Wc = W1; inv_s = 0.5f;  }
    else                 { f = f2 + (size_t)cl * P2; Hc = H2; Wc = W2; inv_s = 0.25f; }
    float acc = 0.0f;
#pragma unroll
    for (int ry = 0; ry < 2; ++ry) {
        float Y = by1 + ((float)oh + 0.25f + 0.5f * ry) * bh;
        bool vy = (Y >= -1.0f) && (Y <= (float)H0);
        float Yc = fminf(fmaxf(Y, 0.0f), (float)(H0 - 1));
        int y0 = (int)Yc;
        float ly = Yc - (float)y0;
#pragma unroll
        for (int rx = 0; rx < 2; ++rx) {
            float X = bx1 + ((float)ow + 0.25f + 0.5f * rx) * bw;
            bool vx = (X >= -1.0f) && (X <= (float)W0);
            float Xc = fminf(fmaxf(X, 0.0f), (float)(W0 - 1));
            int x0 = (int)Xc;
            float lx = Xc - (float)x0;
            float v;
            if (level == 0) {
                int y1i = min(y0 + 1, H0 - 1), x1i = min(x0 + 1, W0 - 1);
                float hy = 1.0f - ly, hx = 1.0f - lx;
                float v00 = f[y0 * W0 + x0],  v01 = f[y0 * W0 + x1i];
                float v10 = f[y1i * W0 + x0], v11 = f[y1i * W0 + x1i];
                v = hy * (hx * v00 + lx * v01) + ly * (hx * v10 + lx * v11);
            } else {
                int yb, xb; float wy[3], wxl[3];
                axis_w3_fb(y0, H0, Hc, inv_s, ly, yb, wy);
                axis_w3_fb(x0, W0, Wc, inv_s, lx, xb, wxl);
                v = 0.0f;
#pragma unroll
                for (int a = 0; a < 3; ++a) {
                    int row = min(yb + a, Hc - 1) * Wc;
                    float s = 0.0f;
#pragma unroll
                    for (int b = 0; b < 3; ++b)
                        s += wxl[b] * f[row + min(xb + b, Wc - 1)];
                    v += wy[a] * s;
                }
            }
            if (vy && vx) acc += v;
        }
    }
    out[i] = acc * 0.25f;
}

// ---------------- launch ----------------------------------------------------
extern "C" void kernel_launch(void* const* d_in, const int* in_sizes, int n_in,
                              void* d_out, int out_size, void* d_ws, size_t ws_size,
                              hipStream_t stream) {
    const float* f0    = (const float*)d_in[0];
    const float* f1    = (const float*)d_in[1];
    const float* f2    = (const float*)d_in[2];
    const float* boxes = (const float*)d_in[3];
    const int* img_h_p = (const int*)d_in[4];
    const int* img_w_p = (const int*)d_in[5];
    float* out = (float*)d_out;
    int N = in_sizes[3] / 4;

    if (ws_size >= WS_BYTES) {
        float* ws = (float*)d_ws;
        float* T0 = ws + T0_OFF;
        float* T1 = ws + T1_OFF;
        float* T2 = ws + T2_OFF;
        transpose_cl_kernel<<<dim3((P0 + 63) / 64, 4), 256, 0, stream>>>(f0, T0, P0);
        transpose_cl_kernel<<<dim3((P1 + 63) / 64, 4), 256, 0, stream>>>(f1, T1, P1);
        transpose_cl_kernel<<<dim3((P2 + 63) / 64, 4), 256, 0, stream>>>(f2, T2, P2);
        roi_align_cl_kernel<<<dim3(N, 12), 256, 0, stream>>>(
            T0, T1, T2, boxes, img_h_p, img_w_p, out);
    } else {
        int total = N * CTOT * OH * OW;
        roi_align_fused_fb_kernel<<<(total + 255) / 256, 256, 0, stream>>>(
            f0, f1, f2, boxes, img_h_p, img_w_p, out, total);
    }
}

// Round 4
// 207.639 us; speedup vs baseline: 2.0942x; 1.4305x over previous
//
#include <hip/hip_runtime.h>
#include <hip/hip_bf16.h>

#define H0 200
#define W0 304
#define H1 100
#define W1 152
#define H2 50
#define W2 76
#define CPL 256   // channels per level
#define CTOT 768
#define OH 7
#define OW 7
#define NPOS 49

#define P0 (H0*W0)   // 60800
#define P1 (H1*W1)   // 15200
#define P2 (H2*W2)   // 3800
#define T0_OFF ((size_t)0)
#define T1_OFF ((size_t)P0*CPL)
#define T2_OFF ((size_t)P0*CPL + (size_t)P1*CPL)
#define WS_ELEMS ((size_t)P0*CPL + (size_t)P1*CPL + (size_t)P2*CPL)
#define WS_BYTES (WS_ELEMS * 4)   // 81,715,200 B

__device__ __forceinline__ float hat01(float d) {
    return fmaxf(0.0f, 1.0f - fabsf(d));
}

// ------------- Stage 1: fused [C][P] -> [P][C] transpose, all 3 levels ------
// 64p x 64c tile per block; float4 global loads (along p) and float4 global
// stores (along c) through an LDS tile.
__global__ void __launch_bounds__(256)
transpose_all_kernel(const float* __restrict__ f0, const float* __restrict__ f1,
                     const float* __restrict__ f2,
                     float* __restrict__ T0, float* __restrict__ T1,
                     float* __restrict__ T2, int n0, int n01) {
    __shared__ float tile[64][68];   // [p_local][c_local], pad keeps 16B align
    int b = blockIdx.x;
    const float* in; float* outp; int P; int rel;
    if (b < n0)       { in = f0; outp = T0; P = P0; rel = b; }
    else if (b < n01) { in = f1; outp = T1; P = P1; rel = b - n0; }
    else              { in = f2; outp = T2; P = P2; rel = b - n01; }
    int p0 = (rel >> 2) * 64;
    int c0 = (rel & 3) * 64;

    int q = threadIdx.x & 15;     // p-quad / c-quad
    int r = threadIdx.x >> 4;     // 0..15
    bool full = (p0 + 64 <= P);
#pragma unroll
    for (int i = 0; i < 4; ++i) {
        int c = c0 + r + 16 * i;
        int p = p0 + 4 * q;
        float4 v;
        if (full) {
            v = *(const float4*)(in + (size_t)c * P + p);
        } else {
            v.x = (p + 0 < P) ? in[(size_t)c * P + p + 0] : 0.0f;
            v.y = (p + 1 < P) ? in[(size_t)c * P + p + 1] : 0.0f;
            v.z = (p + 2 < P) ? in[(size_t)c * P + p + 2] : 0.0f;
            v.w = (p + 3 < P) ? in[(size_t)c * P + p + 3] : 0.0f;
        }
        tile[4 * q + 0][r + 16 * i] = v.x;
        tile[4 * q + 1][r + 16 * i] = v.y;
        tile[4 * q + 2][r + 16 * i] = v.z;
        tile[4 * q + 3][r + 16 * i] = v.w;
    }
    __syncthreads();
#pragma unroll
    for (int i = 0; i < 4; ++i) {
        int p = p0 + r + 16 * i;
        if (p < P) {
            float4 w = *(const float4*)&tile[r + 16 * i][4 * q];
            *(float4*)(outp + (size_t)p * CPL + c0 + 4 * q) = w;
        }
    }
}

// ------------- Stage 2: channels-last RoIAlign, float4 per lane -------------
// block = (box, level); 512 threads = 8 waves; wave handles pos = wv, wv+8,...
// lane carries channels [4*lane, 4*lane+4) -> one wave covers all 256 ch.
// Per-axis tap windows (idx pre-clamped+pre-scaled, weights with validity
// folded) are built once per block by threads 0..13 into LDS:
//   level 0: 4 taps (2 samples x 2 corners);  level 1: <=6;  level 2: <=5.
__global__ void __launch_bounds__(512)
roi_align_cl2_kernel(const float* __restrict__ T0, const float* __restrict__ T1,
                     const float* __restrict__ T2,
                     const float* __restrict__ boxes,
                     const int* __restrict__ img_h_p,
                     const int* __restrict__ img_w_p,
                     float* __restrict__ out) {
    __shared__ float sout[NPOS][260];
    __shared__ int   s_cnt[14];
    __shared__ int   s_idx[14][6];
    __shared__ float s_w[14][6];

    int n = blockIdx.x;
    int level = blockIdx.y;
    const float* T; int Hc, Wc; float inv_s;
    if (level == 0)      { T = T0; Hc = H0; Wc = W0; inv_s = 1.0f;  }
    else if (level == 1) { T = T1; Hc = H1; Wc = W1; inv_s = 0.5f;  }
    else                 { T = T2; Hc = H2; Wc = W2; inv_s = 0.25f; }

    int tid = threadIdx.x;
    if (tid < 14) {
        int axis = (tid >= 7) ? 1 : 0;   // 0 = y, 1 = x
        int o = tid - axis * 7;
        float sx = (float)W0 / (float)img_w_p[0];
        float sy = (float)H0 / (float)img_h_p[0];
        float a1, bs; int Hf, Hca, mul;
        if (axis) {
            a1 = boxes[n * 4 + 0] * sx;
            float a2 = boxes[n * 4 + 2] * sx;
            bs = fmaxf(a2 - a1, 1.0f) * (1.0f / (float)OW);
            Hf = W0; Hca = Wc; mul = 1;
        } else {
            a1 = boxes[n * 4 + 1] * sy;
            float a2 = boxes[n * 4 + 3] * sy;
            bs = fmaxf(a2 - a1, 1.0f) * (1.0f / (float)OH);
            Hf = H0; Hca = Hc; mul = Wc;
        }
        int cnt;
        int idx[6]; float w[6];
#pragma unroll
        for (int j = 0; j < 6; ++j) { idx[j] = 0; w[j] = 0.0f; }
        if (level == 0) {
            cnt = 4;
#pragma unroll
            for (int r2 = 0; r2 < 2; ++r2) {
                float Y = a1 + ((float)o + 0.25f + 0.5f * (float)r2) * bs;
                float v = (Y >= -1.0f && Y <= (float)Hf) ? 1.0f : 0.0f;
                float Yc = fminf(fmaxf(Y, 0.0f), (float)(Hf - 1));
                int y0 = (int)Yc; float lf = Yc - (float)y0;
                idx[2 * r2]     = y0;                 w[2 * r2]     = (1.0f - lf) * v;
                idx[2 * r2 + 1] = min(y0 + 1, Hf - 1); w[2 * r2 + 1] = lf * v;
            }
        } else {
            int bases[2]; float w3[2][3];
#pragma unroll
            for (int r2 = 0; r2 < 2; ++r2) {
                float Y = a1 + ((float)o + 0.25f + 0.5f * (float)r2) * bs;
                float v = (Y >= -1.0f && Y <= (float)Hf) ? 1.0f : 0.0f;
                float Yc = fminf(fmaxf(Y, 0.0f), (float)(Hf - 1));
                int y0 = (int)Yc; float lf = Yc - (float)y0; float hf = 1.0f - lf;
                int yf1 = min(y0 + 1, Hf - 1);
                float yc0 = fminf(fmaxf(((float)y0 + 0.5f) * inv_s - 0.5f, 0.0f), (float)(Hca - 1));
                float yc1 = fminf(fmaxf(((float)yf1 + 0.5f) * inv_s - 0.5f, 0.0f), (float)(Hca - 1));
                int b2 = (int)yc0;
                bases[r2] = b2;
#pragma unroll
                for (int t2 = 0; t2 < 3; ++t2) {
                    float j2 = (float)(b2 + t2);
                    w3[r2][t2] = v * (hf * hat01(yc0 - j2) + lf * hat01(yc1 - j2));
                }
            }
            int d = min(max(bases[1] - bases[0], 0), 3);
            cnt = d + 3;
            w[0] += w3[0][0]; w[1] += w3[0][1]; w[2] += w3[0][2];
            w[d] += w3[1][0]; w[d + 1] += w3[1][1]; w[d + 2] += w3[1][2];
#pragma unroll
            for (int j = 0; j < 6; ++j) idx[j] = min(bases[0] + j, Hca - 1);
        }
        s_cnt[tid] = cnt;
#pragma unroll
        for (int j = 0; j < 6; ++j) { s_idx[tid][j] = idx[j] * mul; s_w[tid][j] = w[j]; }
    }
    __syncthreads();

    int lane = tid & 63;
    int wv = tid >> 6;                 // 0..7
    int coff = lane * 4;               // channel offset within level
    for (int pos = wv; pos < NPOS; pos += 8) {
        int oh = pos / 7;
        int ow = pos - oh * 7;
        int ycnt = s_cnt[oh];
        int xcnt = s_cnt[7 + ow];
        float a0 = 0.0f, a1 = 0.0f, a2 = 0.0f, a3 = 0.0f;
#pragma unroll
        for (int a = 0; a < 6; ++a) {
            if (a < ycnt) {
                int ry = s_idx[oh][a];
                float wya = s_w[oh][a];
                float s0 = 0.0f, s1 = 0.0f, s2 = 0.0f, s3 = 0.0f;
#pragma unroll
                for (int bb = 0; bb < 6; ++bb) {
                    if (bb < xcnt) {
                        int off = ry + s_idx[7 + ow][bb];
                        float4 v = *(const float4*)(T + (size_t)off * CPL + coff);
                        float wxb = s_w[7 + ow][bb];
                        s0 += wxb * v.x; s1 += wxb * v.y;
                        s2 += wxb * v.z; s3 += wxb * v.w;
                    }
                }
                a0 += wya * s0; a1 += wya * s1; a2 += wya * s2; a3 += wya * s3;
            }
        }
        float4 res;
        res.x = a0 * 0.25f; res.y = a1 * 0.25f;
        res.z = a2 * 0.25f; res.w = a3 * 0.25f;
        *(float4*)&sout[pos][coff] = res;
    }
    __syncthreads();

    size_t obase = ((size_t)n * CTOT + (size_t)level * CPL) * NPOS;
    for (int i2 = tid; i2 < CPL * NPOS; i2 += 512) {
        int c = i2 / NPOS;
        int p = i2 - c * NPOS;
        out[obase + i2] = sout[p][c];
    }
}

// ---------------- Fallback (R1 kernel) if ws too small ----------------------
__device__ __forceinline__ void axis_w3_fb(int yf0, int Hf, int Hc, float inv_s,
                                           float lf, int& base, float* w) {
    int yf1 = min(yf0 + 1, Hf - 1);
    float hf = 1.0f - lf;
    float yc0 = fminf(fmaxf(((float)yf0 + 0.5f) * inv_s - 0.5f, 0.0f), (float)(Hc - 1));
    float yc1 = fminf(fmaxf(((float)yf1 + 0.5f) * inv_s - 0.5f, 0.0f), (float)(Hc - 1));
    base = (int)yc0;
#pragma unroll
    for (int r = 0; r < 3; ++r) {
        float j = (float)(base + r);
        w[r] = hf * hat01(yc0 - j) + lf * hat01(yc1 - j);
    }
}

__global__ void __launch_bounds__(256)
roi_align_fused_fb_kernel(const float* __restrict__ f0,
                          const float* __restrict__ f1,
                          const float* __restrict__ f2,
                          const float* __restrict__ boxes,
                          const int* __restrict__ img_h_p,
                          const int* __restrict__ img_w_p,
                          float* __restrict__ out,
                          int total) {
    int i = blockIdx.x * blockDim.x + threadIdx.x;
    if (i >= total) return;
    int ow = i % OW;
    int t = i / OW;
    int oh = t % OH; t /= OH;
    int c = t % CTOT;
    int n = t / CTOT;
    float sx = (float)W0 / (float)img_w_p[0];
    float sy = (float)H0 / (float)img_h_p[0];
    float bx1 = boxes[n * 4 + 0] * sx;
    float by1 = boxes[n * 4 + 1] * sy;
    float bw = fmaxf(boxes[n * 4 + 2] * sx - bx1, 1.0f) / OW;
    float bh = fmaxf(boxes[n * 4 + 3] * sy - by1, 1.0f) / OH;
    int level = c >> 8;
    int cl = c & (CPL - 1);
    const float* f;
    int Hc, Wc; float inv_s;
    if (level == 0)      { f = f0 + (size_t)cl * P0; Hc = H0; Wc = W0; inv_s = 1.0f;  }
    else if (level == 1) { f = f1 + (size_t)cl * P1; Hc = H1; Wc = W1; inv_s = 0.5f;  }
    else                 { f = f2 + (size_t)cl * P2; Hc = H2; Wc = W2; inv_s = 0.25f; }
    float acc = 0.0f;
#pragma unroll
    for (int ry = 0; ry < 2; ++ry) {
        float Y = by1 + ((float)oh + 0.25f + 0.5f * ry) * bh;
        bool vy = (Y >= -1.0f) && (Y <= (float)H0);
        float Yc = fminf(fmaxf(Y, 0.0f), (float)(H0 - 1));
        int y0 = (int)Yc;
        float ly = Yc - (float)y0;
#pragma unroll
        for (int rx = 0; rx < 2; ++rx) {
            float X = bx1 + ((float)ow + 0.25f + 0.5f * rx) * bw;
            bool vx = (X >= -1.0f) && (X <= (float)W0);
            float Xc = fminf(fmaxf(X, 0.0f), (float)(W0 - 1));
            int x0 = (int)Xc;
            float lx = Xc - (float)x0;
            float v;
            if (level == 0) {
                int y1i = min(y0 + 1, H0 - 1), x1i = min(x0 + 1, W0 - 1);
                float hy = 1.0f - ly, hx = 1.0f - lx;
                float v00 = f[y0 * W0 + x0],  v01 = f[y0 * W0 + x1i];
                float v10 = f[y1i * W0 + x0], v11 = f[y1i * W0 + x1i];
                v = hy * (hx * v00 + lx * v01) + ly * (hx * v10 + lx * v11);
            } else {
                int yb, xb; float wy[3], wxl[3];
                axis_w3_fb(y0, H0, Hc, inv_s, ly, yb, wy);
                axis_w3_fb(x0, W0, Wc, inv_s, lx, xb, wxl);
                v = 0.0f;
#pragma unroll
                for (int a = 0; a < 3; ++a) {
                    int row = min(yb + a, Hc - 1) * Wc;
                    float s = 0.0f;
#pragma unroll
                    for (int b = 0; b < 3; ++b)
                        s += wxl[b] * f[row + min(xb + b, Wc - 1)];
                    v += wy[a] * s;
                }
            }
            if (vy && vx) acc += v;
        }
    }
    out[i] = acc * 0.25f;
}

// ---------------- launch ----------------------------------------------------
extern "C" void kernel_launch(void* const* d_in, const int* in_sizes, int n_in,
                              void* d_out, int out_size, void* d_ws, size_t ws_size,
                              hipStream_t stream) {
    const float* f0    = (const float*)d_in[0];
    const float* f1    = (const float*)d_in[1];
    const float* f2    = (const float*)d_in[2];
    const float* boxes = (const float*)d_in[3];
    const int* img_h_p = (const int*)d_in[4];
    const int* img_w_p = (const int*)d_in[5];
    float* out = (float*)d_out;
    int N = in_sizes[3] / 4;

    if (ws_size >= WS_BYTES) {
        float* ws = (float*)d_ws;
        float* T0 = ws + T0_OFF;
        float* T1 = ws + T1_OFF;
        float* T2 = ws + T2_OFF;
        int n0 = ((P0 + 63) / 64) * 4;   // 3800
        int n1 = ((P1 + 63) / 64) * 4;   // 952
        int n2 = ((P2 + 63) / 64) * 4;   // 240
        transpose_all_kernel<<<n0 + n1 + n2, 256, 0, stream>>>(
            f0, f1, f2, T0, T1, T2, n0, n0 + n1);
        roi_align_cl2_kernel<<<dim3(N, 3), 512, 0, stream>>>(
            T0, T1, T2, boxes, img_h_p, img_w_p, out);
    } else {
        int total = N * CTOT * OH * OW;
        roi_align_fused_fb_kernel<<<(total + 255) / 256, 256, 0, stream>>>(
            f0, f1, f2, boxes, img_h_p, img_w_p, out, total);
    }
}

// Round 5
// 196.872 us; speedup vs baseline: 2.2087x; 1.0547x over previous
//
#include <hip/hip_runtime.h>
#include <hip/hip_bf16.h>

#define H0 200
#define W0 304
#define H1 100
#define W1 152
#define H2 50
#define W2 76
#define CPL 256   // channels per level
#define CTOT 768
#define OH 7
#define OW 7
#define NPOS 49

#define P0 (H0*W0)   // 60800
#define P1 (H1*W1)   // 15200
#define P2 (H2*W2)   // 3800
#define T0_OFF ((size_t)0)
#define T1_OFF ((size_t)P0*CPL)
#define T2_OFF ((size_t)P0*CPL + (size_t)P1*CPL)
#define WS_ELEMS ((size_t)P0*CPL + (size_t)P1*CPL + (size_t)P2*CPL)
#define WS_BYTES (WS_ELEMS * 2)   // bf16 workspace: 40,857,600 B

__device__ __forceinline__ float hat01(float d) {
    return fmaxf(0.0f, 1.0f - fabsf(d));
}

__device__ __forceinline__ unsigned short f2bf_rne(float x) {
    unsigned int u = __float_as_uint(x);
    u += 0x7fffu + ((u >> 16) & 1u);
    return (unsigned short)(u >> 16);
}

// ------------- Stage 1: fused [C][P] fp32 -> [P][C] bf16 transpose ----------
// 64p x 64c tile per block; float4 global loads (along p), ushort4 global
// stores (along c) through an LDS tile.
__global__ void __launch_bounds__(256)
transpose_all_kernel(const float* __restrict__ f0, const float* __restrict__ f1,
                     const float* __restrict__ f2,
                     unsigned short* __restrict__ T0,
                     unsigned short* __restrict__ T1,
                     unsigned short* __restrict__ T2, int n0, int n01) {
    __shared__ unsigned short tile[64][72];   // [p_local][c_local]
    int b = blockIdx.x;
    const float* in; unsigned short* outp; int P; int rel;
    if (b < n0)       { in = f0; outp = T0; P = P0; rel = b; }
    else if (b < n01) { in = f1; outp = T1; P = P1; rel = b - n0; }
    else              { in = f2; outp = T2; P = P2; rel = b - n01; }
    int p0 = (rel >> 2) * 64;
    int c0 = (rel & 3) * 64;

    int q = threadIdx.x & 15;     // p-quad / c-quad
    int r = threadIdx.x >> 4;     // 0..15
    bool full = (p0 + 64 <= P);
#pragma unroll
    for (int i = 0; i < 4; ++i) {
        int c = c0 + r + 16 * i;
        int p = p0 + 4 * q;
        float4 v;
        if (full) {
            v = *(const float4*)(in + (size_t)c * P + p);
        } else {
            v.x = (p + 0 < P) ? in[(size_t)c * P + p + 0] : 0.0f;
            v.y = (p + 1 < P) ? in[(size_t)c * P + p + 1] : 0.0f;
            v.z = (p + 2 < P) ? in[(size_t)c * P + p + 2] : 0.0f;
            v.w = (p + 3 < P) ? in[(size_t)c * P + p + 3] : 0.0f;
        }
        tile[4 * q + 0][r + 16 * i] = f2bf_rne(v.x);
        tile[4 * q + 1][r + 16 * i] = f2bf_rne(v.y);
        tile[4 * q + 2][r + 16 * i] = f2bf_rne(v.z);
        tile[4 * q + 3][r + 16 * i] = f2bf_rne(v.w);
    }
    __syncthreads();
#pragma unroll
    for (int i = 0; i < 4; ++i) {
        int p = p0 + r + 16 * i;
        if (p < P) {
            ushort4 w = *(const ushort4*)&tile[r + 16 * i][4 * q];
            *(ushort4*)(outp + (size_t)p * CPL + c0 + 4 * q) = w;
        }
    }
}

// ------------- Stage 2: channels-last RoIAlign, bf16x4 per lane -------------
// block = (box, level); 512 threads = 8 waves; wave handles pos = wv, wv+8,...
// lane carries channels [4*lane, 4*lane+4) -> one wave covers all 256 ch,
// each tap load = 64 lanes x 8B contiguous (512 B).
__global__ void __launch_bounds__(512)
roi_align_cl3_kernel(const unsigned short* __restrict__ T0,
                     const unsigned short* __restrict__ T1,
                     const unsigned short* __restrict__ T2,
                     const float* __restrict__ boxes,
                     const int* __restrict__ img_h_p,
                     const int* __restrict__ img_w_p,
                     float* __restrict__ out) {
    __shared__ float sout[NPOS][260];
    __shared__ int   s_cnt[14];
    __shared__ int   s_idx[14][6];
    __shared__ float s_w[14][6];

    int n = blockIdx.x;
    int level = blockIdx.y;
    const unsigned short* T; int Hc, Wc; float inv_s;
    if (level == 0)      { T = T0; Hc = H0; Wc = W0; inv_s = 1.0f;  }
    else if (level == 1) { T = T1; Hc = H1; Wc = W1; inv_s = 0.5f;  }
    else                 { T = T2; Hc = H2; Wc = W2; inv_s = 0.25f; }

    int tid = threadIdx.x;
    if (tid < 14) {
        int axis = (tid >= 7) ? 1 : 0;   // 0 = y, 1 = x
        int o = tid - axis * 7;
        float sx = (float)W0 / (float)img_w_p[0];
        float sy = (float)H0 / (float)img_h_p[0];
        float a1, bs; int Hf, Hca, mul;
        if (axis) {
            a1 = boxes[n * 4 + 0] * sx;
            float a2 = boxes[n * 4 + 2] * sx;
            bs = fmaxf(a2 - a1, 1.0f) * (1.0f / (float)OW);
            Hf = W0; Hca = Wc; mul = 1;
        } else {
            a1 = boxes[n * 4 + 1] * sy;
            float a2 = boxes[n * 4 + 3] * sy;
            bs = fmaxf(a2 - a1, 1.0f) * (1.0f / (float)OH);
            Hf = H0; Hca = Hc; mul = Wc;
        }
        int cnt;
        int idx[6]; float w[6];
#pragma unroll
        for (int j = 0; j < 6; ++j) { idx[j] = 0; w[j] = 0.0f; }
        if (level == 0) {
            cnt = 4;
#pragma unroll
            for (int r2 = 0; r2 < 2; ++r2) {
                float Y = a1 + ((float)o + 0.25f + 0.5f * (float)r2) * bs;
                float v = (Y >= -1.0f && Y <= (float)Hf) ? 1.0f : 0.0f;
                float Yc = fminf(fmaxf(Y, 0.0f), (float)(Hf - 1));
                int y0 = (int)Yc; float lf = Yc - (float)y0;
                idx[2 * r2]     = y0;                  w[2 * r2]     = (1.0f - lf) * v;
                idx[2 * r2 + 1] = min(y0 + 1, Hf - 1); w[2 * r2 + 1] = lf * v;
            }
        } else {
            int bases[2]; float w3[2][3];
#pragma unroll
            for (int r2 = 0; r2 < 2; ++r2) {
                float Y = a1 + ((float)o + 0.25f + 0.5f * (float)r2) * bs;
                float v = (Y >= -1.0f && Y <= (float)Hf) ? 1.0f : 0.0f;
                float Yc = fminf(fmaxf(Y, 0.0f), (float)(Hf - 1));
                int y0 = (int)Yc; float lf = Yc - (float)y0; float hf = 1.0f - lf;
                int yf1 = min(y0 + 1, Hf - 1);
                float yc0 = fminf(fmaxf(((float)y0 + 0.5f) * inv_s - 0.5f, 0.0f), (float)(Hca - 1));
                float yc1 = fminf(fmaxf(((float)yf1 + 0.5f) * inv_s - 0.5f, 0.0f), (float)(Hca - 1));
                int b2 = (int)yc0;
                bases[r2] = b2;
#pragma unroll
                for (int t2 = 0; t2 < 3; ++t2) {
                    float j2 = (float)(b2 + t2);
                    w3[r2][t2] = v * (hf * hat01(yc0 - j2) + lf * hat01(yc1 - j2));
                }
            }
            int d = min(max(bases[1] - bases[0], 0), 3);
            cnt = d + 3;
            w[0] += w3[0][0]; w[1] += w3[0][1]; w[2] += w3[0][2];
            w[d] += w3[1][0]; w[d + 1] += w3[1][1]; w[d + 2] += w3[1][2];
#pragma unroll
            for (int j = 0; j < 6; ++j) idx[j] = min(bases[0] + j, Hca - 1);
        }
        s_cnt[tid] = cnt;
#pragma unroll
        for (int j = 0; j < 6; ++j) { s_idx[tid][j] = idx[j] * mul; s_w[tid][j] = w[j]; }
    }
    __syncthreads();

    int lane = tid & 63;
    int wv = tid >> 6;                 // 0..7
    int coff = lane * 4;               // channel offset within level
    for (int pos = wv; pos < NPOS; pos += 8) {
        int oh = pos / 7;
        int ow = pos - oh * 7;
        int ycnt = s_cnt[oh];
        int xcnt = s_cnt[7 + ow];
        float a0 = 0.0f, a1 = 0.0f, a2 = 0.0f, a3 = 0.0f;
#pragma unroll
        for (int a = 0; a < 6; ++a) {
            if (a < ycnt) {
                int ry = s_idx[oh][a];
                float wya = s_w[oh][a];
                float s0 = 0.0f, s1 = 0.0f, s2 = 0.0f, s3 = 0.0f;
#pragma unroll
                for (int bb = 0; bb < 6; ++bb) {
                    if (bb < xcnt) {
                        int off = ry + s_idx[7 + ow][bb];
                        uint2 v = *(const uint2*)(T + (size_t)off * CPL + coff);
                        float wxb = s_w[7 + ow][bb];
                        float c0f = __uint_as_float(v.x << 16);
                        float c1f = __uint_as_float(v.x & 0xffff0000u);
                        float c2f = __uint_as_float(v.y << 16);
                        float c3f = __uint_as_float(v.y & 0xffff0000u);
                        s0 += wxb * c0f; s1 += wxb * c1f;
                        s2 += wxb * c2f; s3 += wxb * c3f;
                    }
                }
                a0 += wya * s0; a1 += wya * s1; a2 += wya * s2; a3 += wya * s3;
            }
        }
        float4 res;
        res.x = a0 * 0.25f; res.y = a1 * 0.25f;
        res.z = a2 * 0.25f; res.w = a3 * 0.25f;
        *(float4*)&sout[pos][coff] = res;
    }
    __syncthreads();

    size_t obase = ((size_t)n * CTOT + (size_t)level * CPL) * NPOS;
    for (int i2 = tid; i2 < CPL * NPOS; i2 += 512) {
        int c = i2 / NPOS;
        int p = i2 - c * NPOS;
        out[obase + i2] = sout[p][c];
    }
}

// ---------------- Fallback (R1 kernel) if ws too small ----------------------
__device__ __forceinline__ void axis_w3_fb(int yf0, int Hf, int Hc, float inv_s,
                                           float lf, int& base, float* w) {
    int yf1 = min(yf0 + 1, Hf - 1);
    float hf = 1.0f - lf;
    float yc0 = fminf(fmaxf(((float)yf0 + 0.5f) * inv_s - 0.5f, 0.0f), (float)(Hc - 1));
    float yc1 = fminf(fmaxf(((float)yf1 + 0.5f) * inv_s - 0.5f, 0.0f), (float)(Hc - 1));
    base = (int)yc0;
#pragma unroll
    for (int r = 0; r < 3; ++r) {
        float j = (float)(base + r);
        w[r] = hf * hat01(yc0 - j) + lf * hat01(yc1 - j);
    }
}

__global__ void __launch_bounds__(256)
roi_align_fused_fb_kernel(const float* __restrict__ f0,
                          const float* __restrict__ f1,
                          const float* __restrict__ f2,
                          const float* __restrict__ boxes,
                          const int* __restrict__ img_h_p,
                          const int* __restrict__ img_w_p,
                          float* __restrict__ out,
                          int total) {
    int i = blockIdx.x * blockDim.x + threadIdx.x;
    if (i >= total) return;
    int ow = i % OW;
    int t = i / OW;
    int oh = t % OH; t /= OH;
    int c = t % CTOT;
    int n = t / CTOT;
    float sx = (float)W0 / (float)img_w_p[0];
    float sy = (float)H0 / (float)img_h_p[0];
    float bx1 = boxes[n * 4 + 0] * sx;
    float by1 = boxes[n * 4 + 1] * sy;
    float bw = fmaxf(boxes[n * 4 + 2] * sx - bx1, 1.0f) / OW;
    float bh = fmaxf(boxes[n * 4 + 3] * sy - by1, 1.0f) / OH;
    int level = c >> 8;
    int cl = c & (CPL - 1);
    const float* f;
    int Hc, Wc; float inv_s;
    if (level == 0)      { f = f0 + (size_t)cl * P0; Hc = H0; Wc = W0; inv_s = 1.0f;  }
    else if (level == 1) { f = f1 + (size_t)cl * P1; Hc = H1; Wc = W1; inv_s = 0.5f;  }
    else                 { f = f2 + (size_t)cl * P2; Hc = H2; Wc = W2; inv_s = 0.25f; }
    float acc = 0.0f;
#pragma unroll
    for (int ry = 0; ry < 2; ++ry) {
        float Y = by1 + ((float)oh + 0.25f + 0.5f * ry) * bh;
        bool vy = (Y >= -1.0f) && (Y <= (float)H0);
        float Yc = fminf(fmaxf(Y, 0.0f), (float)(H0 - 1));
        int y0 = (int)Yc;
        float ly = Yc - (float)y0;
#pragma unroll
        for (int rx = 0; rx < 2; ++rx) {
            float X = bx1 + ((float)ow + 0.25f + 0.5f * rx) * bw;
            bool vx = (X >= -1.0f) && (X <= (float)W0);
            float Xc = fminf(fmaxf(X, 0.0f), (float)(W0 - 1));
            int x0 = (int)Xc;
            float lx = Xc - (float)x0;
            float v;
            if (level == 0) {
                int y1i = min(y0 + 1, H0 - 1), x1i = min(x0 + 1, W0 - 1);
                float hy = 1.0f - ly, hx = 1.0f - lx;
                float v00 = f[y0 * W0 + x0],  v01 = f[y0 * W0 + x1i];
                float v10 = f[y1i * W0 + x0], v11 = f[y1i * W0 + x1i];
                v = hy * (hx * v00 + lx * v01) + ly * (hx * v10 + lx * v11);
            } else {
                int yb, xb; float wy[3], wxl[3];
                axis_w3_fb(y0, H0, Hc, inv_s, ly, yb, wy);
                axis_w3_fb(x0, W0, Wc, inv_s, lx, xb, wxl);
                v = 0.0f;
#pragma unroll
                for (int a = 0; a < 3; ++a) {
                    int row = min(yb + a, Hc - 1) * Wc;
                    float s = 0.0f;
#pragma unroll
                    for (int b = 0; b < 3; ++b)
                        s += wxl[b] * f[row + min(xb + b, Wc - 1)];
                    v += wy[a] * s;
                }
            }
            if (vy && vx) acc += v;
        }
    }
    out[i] = acc * 0.25f;
}

// ---------------- launch ----------------------------------------------------
extern "C" void kernel_launch(void* const* d_in, const int* in_sizes, int n_in,
                              void* d_out, int out_size, void* d_ws, size_t ws_size,
                              hipStream_t stream) {
    const float* f0    = (const float*)d_in[0];
    const float* f1    = (const float*)d_in[1];
    const float* f2    = (const float*)d_in[2];
    const float* boxes = (const float*)d_in[3];
    const int* img_h_p = (const int*)d_in[4];
    const int* img_w_p = (const int*)d_in[5];
    float* out = (float*)d_out;
    int N = in_sizes[3] / 4;

    if (ws_size >= WS_BYTES) {
        unsigned short* ws = (unsigned short*)d_ws;
        unsigned short* T0 = ws + T0_OFF;
        unsigned short* T1 = ws + T1_OFF;
        unsigned short* T2 = ws + T2_OFF;
        int n0 = ((P0 + 63) / 64) * 4;   // 3800
        int n1 = ((P1 + 63) / 64) * 4;   // 952
        int n2 = ((P2 + 63) / 64) * 4;   // 240
        transpose_all_kernel<<<n0 + n1 + n2, 256, 0, stream>>>(
            f0, f1, f2, T0, T1, T2, n0, n0 + n1);
        roi_align_cl3_kernel<<<dim3(N, 3), 512, 0, stream>>>(
            T0, T1, T2, boxes, img_h_p, img_w_p, out);
    } else {
        int total = N * CTOT * OH * OW;
        roi_align_fused_fb_kernel<<<(total + 255) / 256, 256, 0, stream>>>(
            f0, f1, f2, boxes, img_h_p, img_w_p, out, total);
    }
}

// Round 6
// 162.772 us; speedup vs baseline: 2.6714x; 1.2095x over previous
//
#include <hip/hip_runtime.h>
#include <hip/hip_bf16.h>

#define H0 200
#define W0 304
#define H1 100
#define W1 152
#define H2 50
#define W2 76
#define CPL 256   // channels per level
#define CTOT 768
#define OH 7
#define OW 7
#define NPOS 49

#define P0 (H0*W0)   // 60800
#define P1 (H1*W1)   // 15200
#define P2 (H2*W2)   // 3800
#define T0_OFF ((size_t)0)
#define T1_OFF ((size_t)P0*CPL)
#define T2_OFF ((size_t)P0*CPL + (size_t)P1*CPL)
#define WS_ELEMS ((size_t)P0*CPL + (size_t)P1*CPL + (size_t)P2*CPL)
#define WS_BYTES (WS_ELEMS * 2)   // bf16 workspace: 40,857,600 B

__device__ __forceinline__ float hat01(float d) {
    return fmaxf(0.0f, 1.0f - fabsf(d));
}

__device__ __forceinline__ unsigned short f2bf_rne(float x) {
    unsigned int u = __float_as_uint(x);
    u += 0x7fffu + ((u >> 16) & 1u);
    return (unsigned short)(u >> 16);
}

// ------------- Stage 1: fused [C][P] fp32 -> [P][C] bf16 transpose ----------
__global__ void __launch_bounds__(256)
transpose_all_kernel(const float* __restrict__ f0, const float* __restrict__ f1,
                     const float* __restrict__ f2,
                     unsigned short* __restrict__ T0,
                     unsigned short* __restrict__ T1,
                     unsigned short* __restrict__ T2, int n0, int n01) {
    __shared__ unsigned short tile[64][72];   // [p_local][c_local]
    int b = blockIdx.x;
    const float* in; unsigned short* outp; int P; int rel;
    if (b < n0)       { in = f0; outp = T0; P = P0; rel = b; }
    else if (b < n01) { in = f1; outp = T1; P = P1; rel = b - n0; }
    else              { in = f2; outp = T2; P = P2; rel = b - n01; }
    int p0 = (rel >> 2) * 64;
    int c0 = (rel & 3) * 64;

    int q = threadIdx.x & 15;     // p-quad / c-quad
    int r = threadIdx.x >> 4;     // 0..15
    bool full = (p0 + 64 <= P);
#pragma unroll
    for (int i = 0; i < 4; ++i) {
        int c = c0 + r + 16 * i;
        int p = p0 + 4 * q;
        float4 v;
        if (full) {
            v = *(const float4*)(in + (size_t)c * P + p);
        } else {
            v.x = (p + 0 < P) ? in[(size_t)c * P + p + 0] : 0.0f;
            v.y = (p + 1 < P) ? in[(size_t)c * P + p + 1] : 0.0f;
            v.z = (p + 2 < P) ? in[(size_t)c * P + p + 2] : 0.0f;
            v.w = (p + 3 < P) ? in[(size_t)c * P + p + 3] : 0.0f;
        }
        tile[4 * q + 0][r + 16 * i] = f2bf_rne(v.x);
        tile[4 * q + 1][r + 16 * i] = f2bf_rne(v.y);
        tile[4 * q + 2][r + 16 * i] = f2bf_rne(v.z);
        tile[4 * q + 3][r + 16 * i] = f2bf_rne(v.w);
    }
    __syncthreads();
#pragma unroll
    for (int i = 0; i < 4; ++i) {
        int p = p0 + r + 16 * i;
        if (p < P) {
            ushort4 w = *(const ushort4*)&tile[r + 16 * i][4 * q];
            *(ushort4*)(outp + (size_t)p * CPL + c0 + 4 * q) = w;
        }
    }
}

// ------------- Stage 2: channels-last RoIAlign, bf16x4 per lane -------------
// Fixed-size, branch-free tap loops. Window (idx pre-scaled to element offset
// incl. CPL, weight zero-padded) copied LDS -> registers once per pos, then
// TYxTX fully-unrolled independent loads: the ILP hides L2 latency.
template<int TY, int TX>
__device__ __forceinline__ float4 accum_pos(const unsigned short* __restrict__ Tc,
                                            const int* yi, const float* yw,
                                            const int* xi, const float* xw) {
    float a0 = 0.0f, a1 = 0.0f, a2 = 0.0f, a3 = 0.0f;
#pragma unroll
    for (int a = 0; a < TY; ++a) {
        float s0 = 0.0f, s1 = 0.0f, s2 = 0.0f, s3 = 0.0f;
#pragma unroll
        for (int b = 0; b < TX; ++b) {
            uint2 v = *(const uint2*)(Tc + (unsigned)(yi[a] + xi[b]));
            float wxb = xw[b];
            s0 += wxb * __uint_as_float(v.x << 16);
            s1 += wxb * __uint_as_float(v.x & 0xffff0000u);
            s2 += wxb * __uint_as_float(v.y << 16);
            s3 += wxb * __uint_as_float(v.y & 0xffff0000u);
        }
        a0 += yw[a] * s0; a1 += yw[a] * s1; a2 += yw[a] * s2; a3 += yw[a] * s3;
    }
    float4 r;
    r.x = a0 * 0.25f; r.y = a1 * 0.25f; r.z = a2 * 0.25f; r.w = a3 * 0.25f;
    return r;
}

template<int TY, int TX>
__device__ __forceinline__ void run_level(const unsigned short* __restrict__ Tc,
                                          const int (*s_idx)[6], const float (*s_w)[6],
                                          float (*sout)[260], int wv, int coff) {
    for (int pos = wv; pos < NPOS; pos += 8) {
        int oh = pos / 7;
        int ow = pos - oh * 7;
        int yi[6], xi[6];
        float yw[6], xw[6];
#pragma unroll
        for (int j = 0; j < 6; ++j) {
            yi[j] = s_idx[oh][j];     yw[j] = s_w[oh][j];
            xi[j] = s_idx[7 + ow][j]; xw[j] = s_w[7 + ow][j];
        }
        float4 res = accum_pos<TY, TX>(Tc, yi, yw, xi, xw);
        *(float4*)&sout[pos][coff] = res;
    }
}

__global__ void __launch_bounds__(512)
roi_align_cl4_kernel(const unsigned short* __restrict__ T0,
                     const unsigned short* __restrict__ T1,
                     const unsigned short* __restrict__ T2,
                     const float* __restrict__ boxes,
                     const int* __restrict__ img_h_p,
                     const int* __restrict__ img_w_p,
                     float* __restrict__ out) {
    __shared__ float sout[NPOS][260];
    __shared__ int   s_idx[14][6];
    __shared__ float s_w[14][6];

    int n = blockIdx.x;
    int level = blockIdx.y;
    const unsigned short* T; int Hc, Wc; float inv_s;
    if (level == 0)      { T = T0; Hc = H0; Wc = W0; inv_s = 1.0f;  }
    else if (level == 1) { T = T1; Hc = H1; Wc = W1; inv_s = 0.5f;  }
    else                 { T = T2; Hc = H2; Wc = W2; inv_s = 0.25f; }

    int tid = threadIdx.x;
    if (tid < 14) {
        int axis = (tid >= 7) ? 1 : 0;   // 0 = y, 1 = x
        int o = tid - axis * 7;
        float sx = (float)W0 / (float)img_w_p[0];
        float sy = (float)H0 / (float)img_h_p[0];
        float a1, bs; int Hf, Hca, mul;
        if (axis) {
            a1 = boxes[n * 4 + 0] * sx;
            float a2 = boxes[n * 4 + 2] * sx;
            bs = fmaxf(a2 - a1, 1.0f) * (1.0f / (float)OW);
            Hf = W0; Hca = Wc; mul = 1;
        } else {
            a1 = boxes[n * 4 + 1] * sy;
            float a2 = boxes[n * 4 + 3] * sy;
            bs = fmaxf(a2 - a1, 1.0f) * (1.0f / (float)OH);
            Hf = H0; Hca = Hc; mul = Wc;
        }
        int idx[6]; float w[6];
#pragma unroll
        for (int j = 0; j < 6; ++j) { idx[j] = 0; w[j] = 0.0f; }
        if (level == 0) {
#pragma unroll
            for (int r2 = 0; r2 < 2; ++r2) {
                float Y = a1 + ((float)o + 0.25f + 0.5f * (float)r2) * bs;
                float v = (Y >= -1.0f && Y <= (float)Hf) ? 1.0f : 0.0f;
                float Yc = fminf(fmaxf(Y, 0.0f), (float)(Hf - 1));
                int y0 = (int)Yc; float lf = Yc - (float)y0;
                idx[2 * r2]     = y0;                  w[2 * r2]     = (1.0f - lf) * v;
                idx[2 * r2 + 1] = min(y0 + 1, Hf - 1); w[2 * r2 + 1] = lf * v;
            }
        } else {
            int bases[2]; float w3[2][3];
#pragma unroll
            for (int r2 = 0; r2 < 2; ++r2) {
                float Y = a1 + ((float)o + 0.25f + 0.5f * (float)r2) * bs;
                float v = (Y >= -1.0f && Y <= (float)Hf) ? 1.0f : 0.0f;
                float Yc = fminf(fmaxf(Y, 0.0f), (float)(Hf - 1));
                int y0 = (int)Yc; float lf = Yc - (float)y0; float hf = 1.0f - lf;
                int yf1 = min(y0 + 1, Hf - 1);
                float yc0 = fminf(fmaxf(((float)y0 + 0.5f) * inv_s - 0.5f, 0.0f), (float)(Hca - 1));
                float yc1 = fminf(fmaxf(((float)yf1 + 0.5f) * inv_s - 0.5f, 0.0f), (float)(Hca - 1));
                int b2 = (int)yc0;
                bases[r2] = b2;
#pragma unroll
                for (int t2 = 0; t2 < 3; ++t2) {
                    float j2 = (float)(b2 + t2);
                    w3[r2][t2] = v * (hf * hat01(yc0 - j2) + lf * hat01(yc1 - j2));
                }
            }
            int dmax = (level == 1) ? 3 : 2;   // geometry: box<=272px -> gap<=2.43/1.21
            int d = min(max(bases[1] - bases[0], 0), dmax);
            w[0] += w3[0][0]; w[1] += w3[0][1]; w[2] += w3[0][2];
            w[d] += w3[1][0]; w[d + 1] += w3[1][1]; w[d + 2] += w3[1][2];
#pragma unroll
            for (int j = 0; j < 6; ++j) idx[j] = min(bases[0] + j, Hca - 1);
        }
        // pre-scale to element offset (row stride incl. CPL; col stride = CPL)
#pragma unroll
        for (int j = 0; j < 6; ++j) { s_idx[tid][j] = idx[j] * mul * CPL; s_w[tid][j] = w[j]; }
    }
    __syncthreads();

    int lane = tid & 63;
    int wv = tid >> 6;                 // 0..7
    int coff = lane * 4;               // channel offset within level
    const unsigned short* Tc = T + coff;

    if (level == 0)      run_level<4, 4>(Tc, s_idx, s_w, sout, wv, coff);
    else if (level == 1) run_level<6, 6>(Tc, s_idx, s_w, sout, wv, coff);
    else                 run_level<5, 5>(Tc, s_idx, s_w, sout, wv, coff);
    __syncthreads();

    size_t obase = ((size_t)n * CTOT + (size_t)level * CPL) * NPOS;
    for (int i2 = tid; i2 < CPL * NPOS; i2 += 512) {
        int c = i2 / NPOS;
        int p = i2 - c * NPOS;
        out[obase + i2] = sout[p][c];
    }
}

// ---------------- Fallback (R1 kernel) if ws too small ----------------------
__device__ __forceinline__ void axis_w3_fb(int yf0, int Hf, int Hc, float inv_s,
                                           float lf, int& base, float* w) {
    int yf1 = min(yf0 + 1, Hf - 1);
    float hf = 1.0f - lf;
    float yc0 = fminf(fmaxf(((float)yf0 + 0.5f) * inv_s - 0.5f, 0.0f), (float)(Hc - 1));
    float yc1 = fminf(fmaxf(((float)yf1 + 0.5f) * inv_s - 0.5f, 0.0f), (float)(Hc - 1));
    base = (int)yc0;
#pragma unroll
    for (int r = 0; r < 3; ++r) {
        float j = (float)(base + r);
        w[r] = hf * hat01(yc0 - j) + lf * hat01(yc1 - j);
    }
}

__global__ void __launch_bounds__(256)
roi_align_fused_fb_kernel(const float* __restrict__ f0,
                          const float* __restrict__ f1,
                          const float* __restrict__ f2,
                          const float* __restrict__ boxes,
                          const int* __restrict__ img_h_p,
                          const int* __restrict__ img_w_p,
                          float* __restrict__ out,
                          int total) {
    int i = blockIdx.x * blockDim.x + threadIdx.x;
    if (i >= total) return;
    int ow = i % OW;
    int t = i / OW;
    int oh = t % OH; t /= OH;
    int c = t % CTOT;
    int n = t / CTOT;
    float sx = (float)W0 / (float)img_w_p[0];
    float sy = (float)H0 / (float)img_h_p[0];
    float bx1 = boxes[n * 4 + 0] * sx;
    float by1 = boxes[n * 4 + 1] * sy;
    float bw = fmaxf(boxes[n * 4 + 2] * sx - bx1, 1.0f) / OW;
    float bh = fmaxf(boxes[n * 4 + 3] * sy - by1, 1.0f) / OH;
    int level = c >> 8;
    int cl = c & (CPL - 1);
    const float* f;
    int Hc, Wc; float inv_s;
    if (level == 0)      { f = f0 + (size_t)cl * P0; Hc = H0; Wc = W0; inv_s = 1.0f;  }
    else if (level == 1) { f = f1 + (size_t)cl * P1; Hc = H1; Wc = W1; inv_s = 0.5f;  }
    else                 { f = f2 + (size_t)cl * P2; Hc = H2; Wc = W2; inv_s = 0.25f; }
    float acc = 0.0f;
#pragma unroll
    for (int ry = 0; ry < 2; ++ry) {
        float Y = by1 + ((float)oh + 0.25f + 0.5f * ry) * bh;
        bool vy = (Y >= -1.0f) && (Y <= (float)H0);
        float Yc = fminf(fmaxf(Y, 0.0f), (float)(H0 - 1));
        int y0 = (int)Yc;
        float ly = Yc - (float)y0;
#pragma unroll
        for (int rx = 0; rx < 2; ++rx) {
            float X = bx1 + ((float)ow + 0.25f + 0.5f * rx) * bw;
            bool vx = (X >= -1.0f) && (X <= (float)W0);
            float Xc = fminf(fmaxf(X, 0.0f), (float)(W0 - 1));
            int x0 = (int)Xc;
            float lx = Xc - (float)x0;
            float v;
            if (level == 0) {
                int y1i = min(y0 + 1, H0 - 1), x1i = min(x0 + 1, W0 - 1);
                float hy = 1.0f - ly, hx = 1.0f - lx;
                float v00 = f[y0 * W0 + x0],  v01 = f[y0 * W0 + x1i];
                float v10 = f[y1i * W0 + x0], v11 = f[y1i * W0 + x1i];
                v = hy * (hx * v00 + lx * v01) + ly * (hx * v10 + lx * v11);
            } else {
                int yb, xb; float wy[3], wxl[3];
                axis_w3_fb(y0, H0, Hc, inv_s, ly, yb, wy);
                axis_w3_fb(x0, W0, Wc, inv_s, lx, xb, wxl);
                v = 0.0f;
#pragma unroll
                for (int a = 0; a < 3; ++a) {
                    int row = min(yb + a, Hc - 1) * Wc;
                    float s = 0.0f;
#pragma unroll
                    for (int b = 0; b < 3; ++b)
                        s += wxl[b] * f[row + min(xb + b, Wc - 1)];
                    v += wy[a] * s;
                }
            }
            if (vy && vx) acc += v;
        }
    }
    out[i] = acc * 0.25f;
}

// ---------------- launch ----------------------------------------------------
extern "C" void kernel_launch(void* const* d_in, const int* in_sizes, int n_in,
                              void* d_out, int out_size, void* d_ws, size_t ws_size,
                              hipStream_t stream) {
    const float* f0    = (const float*)d_in[0];
    const float* f1    = (const float*)d_in[1];
    const float* f2    = (const float*)d_in[2];
    const float* boxes = (const float*)d_in[3];
    const int* img_h_p = (const int*)d_in[4];
    const int* img_w_p = (const int*)d_in[5];
    float* out = (float*)d_out;
    int N = in_sizes[3] / 4;

    if (ws_size >= WS_BYTES) {
        unsigned short* ws = (unsigned short*)d_ws;
        unsigned short* T0 = ws + T0_OFF;
        unsigned short* T1 = ws + T1_OFF;
        unsigned short* T2 = ws + T2_OFF;
        int n0 = ((P0 + 63) / 64) * 4;   // 3800
        int n1 = ((P1 + 63) / 64) * 4;   // 952
        int n2 = ((P2 + 63) / 64) * 4;   // 240
        transpose_all_kernel<<<n0 + n1 + n2, 256, 0, stream>>>(
            f0, f1, f2, T0, T1, T2, n0, n0 + n1);
        roi_align_cl4_kernel<<<dim3(N, 3), 512, 0, stream>>>(
            T0, T1, T2, boxes, img_h_p, img_w_p, out);
    } else {
        int total = N * CTOT * OH * OW;
        roi_align_fused_fb_kernel<<<(total + 255) / 256, 256, 0, stream>>>(
            f0, f1, f2, boxes, img_h_p, img_w_p, out, total);
    }
}